// Round 4
// baseline (524.109 us; speedup 1.0000x reference)
//
#include <hip/hip_runtime.h>
#include <hip/hip_fp16.h>
#include <hip/hip_cooperative_groups.h>
#include <math.h>

namespace cg = cooperative_groups;

#define HS 4096
#define IS 2048
#define NT 4
#define ZD 6144   // HS + IS

typedef float fvec4 __attribute__((ext_vector_type(4)));

__device__ __forceinline__ float wave_reduce(float v) {
#pragma unroll
    for (int off = 32; off > 0; off >>= 1) v += __shfl_xor(v, off, 64);
    return v;
}
__device__ __forceinline__ float sigf(float x) { return 1.0f / (1.0f + expf(-x)); }

static __device__ __forceinline__ float4 ldnt(const float4* p) {
    fvec4 v = __builtin_nontemporal_load(reinterpret_cast<const fvec4*>(p));
    return make_float4(v.x, v.y, v.z, v.w);
}

union U2H { uint2 u; __half2 h[2]; };

// One persistent cooperative kernel. 256 blocks (1/CU) x 512 threads (8 waves).
// Block b owns hidden units [16b, 16b+16); wave w owns units u0=16b+2w, u0+1.
// Per wave: 8 weight rows (4 gates x 2 units). Rows (f,i,c)x2 -> 192 VGPRs fp16;
// rows (o)x2 -> LDS (16 rows/block = 128 KB). weight is read from HBM exactly once.
__global__ __launch_bounds__(512, 2) void lstm_all(
    const float* __restrict__ x,       // [4][2048]
    const int* __restrict__ target,    // [4]
    const float* __restrict__ weight,  // [16384][6144]
    const float* __restrict__ bias,    // [16384]
    const float* __restrict__ W,       // [2048][4096]
    const float* __restrict__ bvec,    // [2048]
    float* __restrict__ out,           // [1]
    float* __restrict__ H,             // [4][4096] ws
    float* __restrict__ logits)        // [4][2048] ws
{
    __shared__ uint2 wlds[16 * 1024];          // 16 rows x 4096 fp16 = 128 KB
    __shared__ __align__(16) float hbuf[HS];   // 16 KB
    __shared__ float gxbuf[8][2][4][4];        // [wave][unit][gate][t]
    __shared__ float cvs[16];                  // cell state per local unit
    __shared__ float red[512];

    const int tid = threadIdx.x;
    const int w = tid >> 6, l = tid & 63;
    const int b = blockIdx.x;
    const int u0 = b * 16 + 2 * w;
    cg::grid_group grid = cg::this_grid();

    // gate order matches reference: f=0, i=1, c=2, o=3 ; row = gate*HS + unit
    int rid[8];
    rid[0] = 0 * HS + u0;     rid[1] = 1 * HS + u0;     rid[2] = 2 * HS + u0;
    rid[3] = 0 * HS + u0 + 1; rid[4] = 1 * HS + u0 + 1; rid[5] = 2 * HS + u0 + 1;
    rid[6] = 3 * HS + u0;     rid[7] = 3 * HS + u0 + 1;
    const int gate_of[8] = {0, 1, 2, 0, 1, 2, 3, 3};
    const int unit_of[8] = {0, 0, 0, 1, 1, 1, 0, 1};

    __half2 wst[6][16][2];   // 192 VGPRs of resident fp16 weights

    // ---------------- Phase A: stream weight once; keep W_h on-chip; x-dots ----
#pragma unroll
    for (int r = 0; r < 8; ++r) {
        const float* wrow = weight + (size_t)rid[r] * ZD;
        const float4* wr4 = reinterpret_cast<const float4*>(wrow);
        if (r < 6) {
#pragma unroll
            for (int j = 0; j < 16; ++j) {
                float4 v = ldnt(&wr4[64 * j + l]);
                wst[r][j][0] = __floats2half2_rn(v.x, v.y);
                wst[r][j][1] = __floats2half2_rn(v.z, v.w);
            }
        } else {
            uint2* dst = wlds + (size_t)(2 * w + (r - 6)) * 1024;
#pragma unroll
            for (int j = 0; j < 16; ++j) {
                float4 v = ldnt(&wr4[64 * j + l]);
                U2H pk;
                pk.h[0] = __floats2half2_rn(v.x, v.y);
                pk.h[1] = __floats2half2_rn(v.z, v.w);
                dst[64 * j + l] = pk.u;
            }
        }
        // x-part dot for all 4 timesteps (x is L1/L2-hot, 32 KB)
        const float4* xr4 = reinterpret_cast<const float4*>(wrow + HS);
        const float4* xv4 = reinterpret_cast<const float4*>(x);
        float a0 = 0.f, a1 = 0.f, a2 = 0.f, a3 = 0.f;
#pragma unroll
        for (int i = 0; i < 8; ++i) {
            float4 wv = ldnt(&xr4[64 * i + l]);
            float4 x0 = xv4[0 * 512 + 64 * i + l];
            float4 x1 = xv4[1 * 512 + 64 * i + l];
            float4 x2 = xv4[2 * 512 + 64 * i + l];
            float4 x3 = xv4[3 * 512 + 64 * i + l];
            a0 += wv.x * x0.x + wv.y * x0.y + wv.z * x0.z + wv.w * x0.w;
            a1 += wv.x * x1.x + wv.y * x1.y + wv.z * x1.z + wv.w * x1.w;
            a2 += wv.x * x2.x + wv.y * x2.y + wv.z * x2.z + wv.w * x2.w;
            a3 += wv.x * x3.x + wv.y * x3.y + wv.z * x3.z + wv.w * x3.w;
        }
        a0 = wave_reduce(a0); a1 = wave_reduce(a1);
        a2 = wave_reduce(a2); a3 = wave_reduce(a3);
        if (l == 0) {
            const float bb = bias[rid[r]];
            gxbuf[w][unit_of[r]][gate_of[r]][0] = a0 + bb;
            gxbuf[w][unit_of[r]][gate_of[r]][1] = a1 + bb;
            gxbuf[w][unit_of[r]][gate_of[r]][2] = a2 + bb;
            gxbuf[w][unit_of[r]][gate_of[r]][3] = a3 + bb;
        }
    }
    __syncthreads();

    // ---------------- Phase B: t=0 (h0=0, c0=0) ----------------
    if (l == 0) {
#pragma unroll
        for (int ui = 0; ui < 2; ++ui) {
            const int u = u0 + ui;
            const float gi = gxbuf[w][ui][1][0];
            const float gc = gxbuf[w][ui][2][0];
            const float go = gxbuf[w][ui][3][0];
            const float cn = tanhf(gc) * sigf(gi);
            cvs[2 * w + ui] = cn;
            H[u] = tanhf(cn) * sigf(go);
        }
    }
    grid.sync();

    // ---------------- Phase C: t = 1..3, W_h resident on-chip ----------------
    for (int t = 1; t < NT; ++t) {
        const float4* hp4 = reinterpret_cast<const float4*>(H + (size_t)(t - 1) * HS);
        float4* hb4 = reinterpret_cast<float4*>(hbuf);
        for (int i = tid; i < HS / 4; i += 512) hb4[i] = hp4[i];
        __syncthreads();

        float acc[8];
#pragma unroll
        for (int r = 0; r < 8; ++r) acc[r] = 0.f;
#pragma unroll
        for (int j = 0; j < 16; ++j) {
            const float4 h4 = hb4[64 * j + l];
#pragma unroll
            for (int r = 0; r < 6; ++r) {
                const __half2 p = wst[r][j][0], q = wst[r][j][1];
                acc[r] += __low2float(p) * h4.x + __high2float(p) * h4.y
                        + __low2float(q) * h4.z + __high2float(q) * h4.w;
            }
#pragma unroll
            for (int r = 6; r < 8; ++r) {
                U2H pk;
                pk.u = wlds[(size_t)(2 * w + (r - 6)) * 1024 + 64 * j + l];
                acc[r] += __low2float(pk.h[0]) * h4.x + __high2float(pk.h[0]) * h4.y
                        + __low2float(pk.h[1]) * h4.z + __high2float(pk.h[1]) * h4.w;
            }
        }
#pragma unroll
        for (int r = 0; r < 8; ++r) acc[r] = wave_reduce(acc[r]);

        if (l == 0) {
#pragma unroll
            for (int ui = 0; ui < 2; ++ui) {
                const int u = u0 + ui;
                const float gf = (ui ? acc[3] : acc[0]) + gxbuf[w][ui][0][t];
                const float gi = (ui ? acc[4] : acc[1]) + gxbuf[w][ui][1][t];
                const float gc = (ui ? acc[5] : acc[2]) + gxbuf[w][ui][2][t];
                const float go = (ui ? acc[7] : acc[6]) + gxbuf[w][ui][3][t];
                const float cn = cvs[2 * w + ui] * sigf(gf) + tanhf(gc) * sigf(gi);
                cvs[2 * w + ui] = cn;
                H[(size_t)t * HS + u] = tanhf(cn) * sigf(go);
            }
        }
        grid.sync();
    }

    // ---------------- Phase D: logits (1 row per wave, 256*8 = 2048) ----------
    {
        const int row = b * 8 + w;
        const float4* wr4 = reinterpret_cast<const float4*>(W + (size_t)row * HS);
        const float4* H4 = reinterpret_cast<const float4*>(H);
        float a0 = 0.f, a1 = 0.f, a2 = 0.f, a3 = 0.f;
#pragma unroll
        for (int i = 0; i < 16; ++i) {
            const float4 wv = ldnt(&wr4[64 * i + l]);
            const float4 h0 = H4[0 * 1024 + 64 * i + l];
            const float4 h1 = H4[1 * 1024 + 64 * i + l];
            const float4 h2 = H4[2 * 1024 + 64 * i + l];
            const float4 h3 = H4[3 * 1024 + 64 * i + l];
            a0 += wv.x * h0.x + wv.y * h0.y + wv.z * h0.z + wv.w * h0.w;
            a1 += wv.x * h1.x + wv.y * h1.y + wv.z * h1.z + wv.w * h1.w;
            a2 += wv.x * h2.x + wv.y * h2.y + wv.z * h2.z + wv.w * h2.w;
            a3 += wv.x * h3.x + wv.y * h3.y + wv.z * h3.z + wv.w * h3.w;
        }
        a0 = wave_reduce(a0); a1 = wave_reduce(a1);
        a2 = wave_reduce(a2); a3 = wave_reduce(a3);
        if (l == 0) {
            const float bv = bvec[row];
            logits[0 * IS + row] = a0 + bv;
            logits[1 * IS + row] = a1 + bv;
            logits[2 * IS + row] = a2 + bv;
            logits[3 * IS + row] = a3 + bv;
        }
    }
    grid.sync();

    // ---------------- Phase E: loss (block 0) ----------------
    if (b == 0) {
        float total = 0.f;
        for (int t = 0; t < NT; ++t) {
            const float* row = logits + (size_t)t * IS;
            float m = -1e30f;
            for (int r = tid; r < IS; r += 512) m = fmaxf(m, row[r]);
            red[tid] = m;
            __syncthreads();
            for (int s = 256; s > 0; s >>= 1) {
                if (tid < s) red[tid] = fmaxf(red[tid], red[tid + s]);
                __syncthreads();
            }
            m = red[0];
            __syncthreads();
            float sum = 0.f;
            for (int r = tid; r < IS; r += 512) sum += expf(row[r] - m);
            red[tid] = sum;
            __syncthreads();
            for (int s = 256; s > 0; s >>= 1) {
                if (tid < s) red[tid] += red[tid + s];
                __syncthreads();
            }
            if (tid == 0) total += (m + logf(red[0])) - row[target[t]];
            __syncthreads();
        }
        if (tid == 0) out[0] = total;
    }
}

extern "C" void kernel_launch(void* const* d_in, const int* in_sizes, int n_in,
                              void* d_out, int out_size, void* d_ws, size_t ws_size,
                              hipStream_t stream) {
    const float* x      = (const float*)d_in[0];   // [4][1][2048]
    const int*   target = (const int*)  d_in[1];   // [4][1]
    const float* weight = (const float*)d_in[2];   // [16384][6144]
    const float* bias   = (const float*)d_in[3];   // [16384]
    const float* W      = (const float*)d_in[4];   // [2048][4096]
    const float* bvec   = (const float*)d_in[5];   // [2048]
    float* out = (float*)d_out;

    float* H      = (float*)d_ws;                  // 4*4096 floats
    float* logits = (float*)d_ws + 4 * HS;         // 4*2048 floats

    void* args[] = {(void*)&x, (void*)&target, (void*)&weight, (void*)&bias,
                    (void*)&W, (void*)&bvec, (void*)&out, (void*)&H, (void*)&logits};
    (void)hipLaunchCooperativeKernel((void*)lstm_all, dim3(256), dim3(512), args, 0, stream);
}

// Round 5
// 434.565 us; speedup vs baseline: 1.2061x; 1.2061x over previous
//
#include <hip/hip_runtime.h>
#include <hip/hip_fp16.h>
#include <hip/hip_cooperative_groups.h>
#include <math.h>

namespace cg = cooperative_groups;

#define HS 4096
#define IS 2048
#define NT 4
#define ZD 6144   // HS + IS

typedef float fvec4 __attribute__((ext_vector_type(4)));
typedef float ef2 __attribute__((ext_vector_type(2)));

__device__ __forceinline__ float wave_reduce(float v) {
#pragma unroll
    for (int off = 32; off > 0; off >>= 1) v += __shfl_xor(v, off, 64);
    return v;
}
__device__ __forceinline__ float sigf(float x) { return 1.0f / (1.0f + expf(-x)); }

static __device__ __forceinline__ float4 ldnt(const float4* p) {
    fvec4 v = __builtin_nontemporal_load(reinterpret_cast<const fvec4*>(p));
    return make_float4(v.x, v.y, v.z, v.w);
}

union U2H { uint2 u; __half2 h[2]; };

// Load one resident W_h row into a named 16-int fp8-packed array (static idx).
#define LOAD_RES_ROW(arr, ridx) do {                                           \
    const float4* wr4_ = reinterpret_cast<const float4*>(weight + (size_t)(ridx) * ZD); \
    _Pragma("unroll")                                                          \
    for (int j = 0; j < 16; ++j) {                                             \
        float4 v_ = ldnt(&wr4_[64 * j + l]);                                   \
        int u_ = __builtin_amdgcn_cvt_pk_fp8_f32(v_.x, v_.y, 0, false);        \
        arr[j] = __builtin_amdgcn_cvt_pk_fp8_f32(v_.z, v_.w, u_, true);        \
    }                                                                          \
} while (0)

// Accumulate one packed-fp8 dword against float4 h.
#define ACC_RES(arr, accv) {                                                   \
    ef2 lo_ = __builtin_amdgcn_cvt_pk_f32_fp8(arr[j], false);                  \
    ef2 hi_ = __builtin_amdgcn_cvt_pk_f32_fp8(arr[j], true);                   \
    accv += lo_.x * h4.x + lo_.y * h4.y + hi_.x * h4.z + hi_.y * h4.w;         \
}

// One persistent cooperative kernel. 256 blocks (1/CU) x 512 threads (8 waves).
// Block b owns hidden units [16b, 16b+16); wave w owns units u0=16b+2w, u0+1.
// Per wave 8 weight rows: (f,i,c)x2 -> fp8 in 96 VGPRs; (o)x2 -> fp16 in LDS.
// weight is read from HBM exactly once.
__global__ __launch_bounds__(512, 2) void lstm_all(
    const float* __restrict__ x,       // [4][2048]
    const int* __restrict__ target,    // [4]
    const float* __restrict__ weight,  // [16384][6144]
    const float* __restrict__ bias,    // [16384]
    const float* __restrict__ W,       // [2048][4096]
    const float* __restrict__ bvec,    // [2048]
    float* __restrict__ out,           // [1]
    float* __restrict__ H,             // [4][4096] ws
    float* __restrict__ logits)        // [4][2048] ws
{
    __shared__ uint2 wlds[16 * 1024];          // 16 rows x 4096 fp16 = 128 KB
    __shared__ __align__(16) float hbuf[HS];   // 16 KB
    __shared__ float gxbuf[8][2][4][4];        // [wave][unit][gate][t]
    __shared__ float cvs[16];                  // cell state per local unit
    __shared__ float red[512];

    const int tid = threadIdx.x;
    const int w = tid >> 6, l = tid & 63;
    const int b = blockIdx.x;
    const int u0 = b * 16 + 2 * w;
    cg::grid_group grid = cg::this_grid();

    // gate order: f=0, i=1, c=2, o=3 ; row = gate*HS + unit
    int wr0[16], wr1[16], wr2[16], wr3[16], wr4r[16], wr5[16];

    // ---------------- Phase A1: resident W_h load (fp8 regs + fp16 LDS) -------
    LOAD_RES_ROW(wr0, 0 * HS + u0);
    LOAD_RES_ROW(wr1, 1 * HS + u0);
    LOAD_RES_ROW(wr2, 2 * HS + u0);
    LOAD_RES_ROW(wr3, 0 * HS + u0 + 1);
    LOAD_RES_ROW(wr4r, 1 * HS + u0 + 1);
    LOAD_RES_ROW(wr5, 2 * HS + u0 + 1);
#pragma unroll
    for (int k = 0; k < 2; ++k) {   // o-gate rows -> LDS fp16
        const float4* wr4_ = reinterpret_cast<const float4*>(weight + (size_t)(3 * HS + u0 + k) * ZD);
        uint2* dst = wlds + (size_t)(2 * w + k) * 1024;
#pragma unroll
        for (int j = 0; j < 16; ++j) {
            float4 v = ldnt(&wr4_[64 * j + l]);
            U2H pk;
            pk.h[0] = __floats2half2_rn(v.x, v.y);
            pk.h[1] = __floats2half2_rn(v.z, v.w);
            dst[64 * j + l] = pk.u;
        }
    }

    // ---------------- Phase A2: x-dots for the 8 rows, all 4 timesteps --------
    {
        int rid[8];
        rid[0] = 0 * HS + u0;     rid[1] = 1 * HS + u0;     rid[2] = 2 * HS + u0;
        rid[3] = 0 * HS + u0 + 1; rid[4] = 1 * HS + u0 + 1; rid[5] = 2 * HS + u0 + 1;
        rid[6] = 3 * HS + u0;     rid[7] = 3 * HS + u0 + 1;
        const int gate_of[8] = {0, 1, 2, 0, 1, 2, 3, 3};
        const int unit_of[8] = {0, 0, 0, 1, 1, 1, 0, 1};
        const float4* xv4 = reinterpret_cast<const float4*>(x);
#pragma unroll
        for (int r = 0; r < 8; ++r) {
            const float4* xr4 = reinterpret_cast<const float4*>(weight + (size_t)rid[r] * ZD + HS);
            float a0 = 0.f, a1 = 0.f, a2 = 0.f, a3 = 0.f;
#pragma unroll
            for (int i = 0; i < 8; ++i) {
                float4 wv = ldnt(&xr4[64 * i + l]);
                float4 x0 = xv4[0 * 512 + 64 * i + l];
                float4 x1 = xv4[1 * 512 + 64 * i + l];
                float4 x2 = xv4[2 * 512 + 64 * i + l];
                float4 x3 = xv4[3 * 512 + 64 * i + l];
                a0 += wv.x * x0.x + wv.y * x0.y + wv.z * x0.z + wv.w * x0.w;
                a1 += wv.x * x1.x + wv.y * x1.y + wv.z * x1.z + wv.w * x1.w;
                a2 += wv.x * x2.x + wv.y * x2.y + wv.z * x2.z + wv.w * x2.w;
                a3 += wv.x * x3.x + wv.y * x3.y + wv.z * x3.z + wv.w * x3.w;
            }
            a0 = wave_reduce(a0); a1 = wave_reduce(a1);
            a2 = wave_reduce(a2); a3 = wave_reduce(a3);
            if (l == 0) {
                const float bb = bias[rid[r]];
                gxbuf[w][unit_of[r]][gate_of[r]][0] = a0 + bb;
                gxbuf[w][unit_of[r]][gate_of[r]][1] = a1 + bb;
                gxbuf[w][unit_of[r]][gate_of[r]][2] = a2 + bb;
                gxbuf[w][unit_of[r]][gate_of[r]][3] = a3 + bb;
            }
        }
    }
    __syncthreads();

    // ---------------- Phase B: t=0 (h0=0, c0=0) ----------------
    if (l == 0) {
#pragma unroll
        for (int ui = 0; ui < 2; ++ui) {
            const int u = u0 + ui;
            const float gi = gxbuf[w][ui][1][0];
            const float gc = gxbuf[w][ui][2][0];
            const float go = gxbuf[w][ui][3][0];
            const float cn = tanhf(gc) * sigf(gi);
            cvs[2 * w + ui] = cn;
            H[u] = tanhf(cn) * sigf(go);
        }
    }
    grid.sync();

    // ---------------- Phase C: t = 1..3, W_h resident on-chip ----------------
    for (int t = 1; t < NT; ++t) {
        const float4* hp4 = reinterpret_cast<const float4*>(H + (size_t)(t - 1) * HS);
        float4* hb4 = reinterpret_cast<float4*>(hbuf);
        for (int i = tid; i < HS / 4; i += 512) hb4[i] = hp4[i];
        __syncthreads();

        float ac0 = 0.f, ac1 = 0.f, ac2 = 0.f, ac3 = 0.f,
              ac4 = 0.f, ac5 = 0.f, ac6 = 0.f, ac7 = 0.f;
#pragma unroll
        for (int j = 0; j < 16; ++j) {
            const float4 h4 = hb4[64 * j + l];
            ACC_RES(wr0, ac0);
            ACC_RES(wr1, ac1);
            ACC_RES(wr2, ac2);
            ACC_RES(wr3, ac3);
            ACC_RES(wr4r, ac4);
            ACC_RES(wr5, ac5);
            {
                U2H pk; pk.u = wlds[(size_t)(2 * w + 0) * 1024 + 64 * j + l];
                ac6 += __low2float(pk.h[0]) * h4.x + __high2float(pk.h[0]) * h4.y
                     + __low2float(pk.h[1]) * h4.z + __high2float(pk.h[1]) * h4.w;
            }
            {
                U2H pk; pk.u = wlds[(size_t)(2 * w + 1) * 1024 + 64 * j + l];
                ac7 += __low2float(pk.h[0]) * h4.x + __high2float(pk.h[0]) * h4.y
                     + __low2float(pk.h[1]) * h4.z + __high2float(pk.h[1]) * h4.w;
            }
        }
        ac0 = wave_reduce(ac0); ac1 = wave_reduce(ac1); ac2 = wave_reduce(ac2);
        ac3 = wave_reduce(ac3); ac4 = wave_reduce(ac4); ac5 = wave_reduce(ac5);
        ac6 = wave_reduce(ac6); ac7 = wave_reduce(ac7);

        if (l == 0) {
            // unit A (u0): f=ac0 i=ac1 c=ac2 o=ac6 ; unit B: f=ac3 i=ac4 c=ac5 o=ac7
            {
                const float gf = ac0 + gxbuf[w][0][0][t];
                const float gi = ac1 + gxbuf[w][0][1][t];
                const float gc = ac2 + gxbuf[w][0][2][t];
                const float go = ac6 + gxbuf[w][0][3][t];
                const float cn = cvs[2 * w] * sigf(gf) + tanhf(gc) * sigf(gi);
                cvs[2 * w] = cn;
                H[(size_t)t * HS + u0] = tanhf(cn) * sigf(go);
            }
            {
                const float gf = ac3 + gxbuf[w][1][0][t];
                const float gi = ac4 + gxbuf[w][1][1][t];
                const float gc = ac5 + gxbuf[w][1][2][t];
                const float go = ac7 + gxbuf[w][1][3][t];
                const float cn = cvs[2 * w + 1] * sigf(gf) + tanhf(gc) * sigf(gi);
                cvs[2 * w + 1] = cn;
                H[(size_t)t * HS + u0 + 1] = tanhf(cn) * sigf(go);
            }
        }
        grid.sync();
    }

    // ---------------- Phase D: logits (1 row per wave, 256*8 = 2048) ----------
    {
        const int row = b * 8 + w;
        const float4* wrow4 = reinterpret_cast<const float4*>(W + (size_t)row * HS);
        const float4* H4 = reinterpret_cast<const float4*>(H);
        float a0 = 0.f, a1 = 0.f, a2 = 0.f, a3 = 0.f;
#pragma unroll
        for (int i = 0; i < 16; ++i) {
            const float4 wv = ldnt(&wrow4[64 * i + l]);
            const float4 h0 = H4[0 * 1024 + 64 * i + l];
            const float4 h1 = H4[1 * 1024 + 64 * i + l];
            const float4 h2 = H4[2 * 1024 + 64 * i + l];
            const float4 h3 = H4[3 * 1024 + 64 * i + l];
            a0 += wv.x * h0.x + wv.y * h0.y + wv.z * h0.z + wv.w * h0.w;
            a1 += wv.x * h1.x + wv.y * h1.y + wv.z * h1.z + wv.w * h1.w;
            a2 += wv.x * h2.x + wv.y * h2.y + wv.z * h2.z + wv.w * h2.w;
            a3 += wv.x * h3.x + wv.y * h3.y + wv.z * h3.z + wv.w * h3.w;
        }
        a0 = wave_reduce(a0); a1 = wave_reduce(a1);
        a2 = wave_reduce(a2); a3 = wave_reduce(a3);
        if (l == 0) {
            const float bv = bvec[row];
            logits[0 * IS + row] = a0 + bv;
            logits[1 * IS + row] = a1 + bv;
            logits[2 * IS + row] = a2 + bv;
            logits[3 * IS + row] = a3 + bv;
        }
    }
    grid.sync();

    // ---------------- Phase E: loss (block 0) ----------------
    if (b == 0) {
        float total = 0.f;
        for (int t = 0; t < NT; ++t) {
            const float* row = logits + (size_t)t * IS;
            float m = -1e30f;
            for (int r = tid; r < IS; r += 512) m = fmaxf(m, row[r]);
            red[tid] = m;
            __syncthreads();
            for (int s = 256; s > 0; s >>= 1) {
                if (tid < s) red[tid] = fmaxf(red[tid], red[tid + s]);
                __syncthreads();
            }
            m = red[0];
            __syncthreads();
            float sum = 0.f;
            for (int r = tid; r < IS; r += 512) sum += expf(row[r] - m);
            red[tid] = sum;
            __syncthreads();
            for (int s = 256; s > 0; s >>= 1) {
                if (tid < s) red[tid] += red[tid + s];
                __syncthreads();
            }
            if (tid == 0) total += (m + logf(red[0])) - row[target[t]];
            __syncthreads();
        }
        if (tid == 0) out[0] = total;
    }
}

extern "C" void kernel_launch(void* const* d_in, const int* in_sizes, int n_in,
                              void* d_out, int out_size, void* d_ws, size_t ws_size,
                              hipStream_t stream) {
    const float* x      = (const float*)d_in[0];   // [4][1][2048]
    const int*   target = (const int*)  d_in[1];   // [4][1]
    const float* weight = (const float*)d_in[2];   // [16384][6144]
    const float* bias   = (const float*)d_in[3];   // [16384]
    const float* W      = (const float*)d_in[4];   // [2048][4096]
    const float* bvec   = (const float*)d_in[5];   // [2048]
    float* out = (float*)d_out;

    float* H      = (float*)d_ws;                  // 4*4096 floats
    float* logits = (float*)d_ws + 4 * HS;         // 4*2048 floats

    void* args[] = {(void*)&x, (void*)&target, (void*)&weight, (void*)&bias,
                    (void*)&W, (void*)&bvec, (void*)&out, (void*)&H, (void*)&logits};
    (void)hipLaunchCooperativeKernel((void*)lstm_all, dim3(256), dim3(512), args, 0, stream);
}

// Round 6
// 350.156 us; speedup vs baseline: 1.4968x; 1.2411x over previous
//
#include <hip/hip_runtime.h>
#include <hip/hip_fp16.h>
#include <hip/hip_cooperative_groups.h>
#include <math.h>

namespace cg = cooperative_groups;

#define HS 4096
#define IS 2048
#define NT 4
#define ZD 6144   // HS + IS

typedef float fvec4 __attribute__((ext_vector_type(4)));
typedef float ef2 __attribute__((ext_vector_type(2)));

__device__ __forceinline__ float wave_reduce(float v) {
#pragma unroll
    for (int off = 32; off > 0; off >>= 1) v += __shfl_xor(v, off, 64);
    return v;
}
__device__ __forceinline__ float sigf(float x) { return 1.0f / (1.0f + expf(-x)); }

static __device__ __forceinline__ float4 ldnt(const float4* p) {
    fvec4 v = __builtin_nontemporal_load(reinterpret_cast<const fvec4*>(p));
    return make_float4(v.x, v.y, v.z, v.w);
}

// Load one W_h row into a named 16-dword fp8-packed register array (static idx).
#define STAGE_REG_ROW(arr, ridx) do {                                          \
    const float4* wr4_ = reinterpret_cast<const float4*>(weight + (size_t)(ridx) * ZD); \
    _Pragma("unroll")                                                          \
    for (int j = 0; j < 16; ++j) {                                             \
        float4 v_ = ldnt(&wr4_[64 * j + l]);                                   \
        int u_ = __builtin_amdgcn_cvt_pk_fp8_f32(v_.x, v_.y, 0, false);        \
        arr[j] = __builtin_amdgcn_cvt_pk_fp8_f32(v_.z, v_.w, u_, true);        \
    }                                                                          \
} while (0)

// Load one W_h row into LDS slot (fp8-packed dwords).
#define STAGE_LDS_ROW(slot, ridx) do {                                         \
    const float4* wr4_ = reinterpret_cast<const float4*>(weight + (size_t)(ridx) * ZD); \
    unsigned int* dst_ = wlds + (size_t)(slot) * 1024;                         \
    _Pragma("unroll")                                                          \
    for (int j = 0; j < 16; ++j) {                                             \
        float4 v_ = ldnt(&wr4_[64 * j + l]);                                   \
        int u_ = __builtin_amdgcn_cvt_pk_fp8_f32(v_.x, v_.y, 0, false);        \
        dst_[64 * j + l] = (unsigned int)__builtin_amdgcn_cvt_pk_fp8_f32(v_.z, v_.w, u_, true); \
    }                                                                          \
} while (0)

// Accumulate one packed-fp8 dword (register row) against float4 h.
#define ACC_REG(arr, accv) {                                                   \
    ef2 lo_ = __builtin_amdgcn_cvt_pk_f32_fp8((int)arr[j], false);             \
    ef2 hi_ = __builtin_amdgcn_cvt_pk_f32_fp8((int)arr[j], true);              \
    accv += lo_.x * h4.x + lo_.y * h4.y + hi_.x * h4.z + hi_.y * h4.w;         \
}

// Accumulate one packed-fp8 dword (LDS row) against float4 h.
#define ACC_LDS(slot, accv) {                                                  \
    int u_ = (int)wlds[(size_t)(slot) * 1024 + 64 * j + l];                    \
    ef2 lo_ = __builtin_amdgcn_cvt_pk_f32_fp8(u_, false);                      \
    ef2 hi_ = __builtin_amdgcn_cvt_pk_f32_fp8(u_, true);                       \
    accv += lo_.x * h4.x + lo_.y * h4.y + hi_.x * h4.z + hi_.y * h4.w;         \
}

// One persistent cooperative kernel. 256 blocks (1/CU) x 512 threads (8 waves).
// Block b owns hidden units [16b, 16b+16); wave w owns units u0=16b+2w, u0+1.
// Per wave 8 W_h rows (4 gates x 2 units), all fp8: (f,i)x2 -> 64 VGPRs;
// (c,o)x2 -> LDS (32 rows/block = 128 KB). weight read from HBM exactly once.
__global__ __launch_bounds__(512) void lstm_all(
    const float* __restrict__ x,       // [4][2048]
    const int* __restrict__ target,    // [4]
    const float* __restrict__ weight,  // [16384][6144]
    const float* __restrict__ bias,    // [16384]
    const float* __restrict__ W,       // [2048][4096]
    const float* __restrict__ bvec,    // [2048]
    float* __restrict__ out,           // [1]
    float* __restrict__ H,             // [4][4096] ws
    float* __restrict__ logits)        // [4][2048] ws
{
    __shared__ unsigned int wlds[32 * 1024];   // 32 fp8 rows x 4 KB = 128 KB
    __shared__ __align__(16) float hbuf[HS];   // 16 KB
    __shared__ float gxbuf[8][2][4][4];        // [wave][unit][gate][t]
    __shared__ float cvs[16];
    __shared__ float red[512];

    const int tid = threadIdx.x;
    const int w = tid >> 6, l = tid & 63;
    const int b = blockIdx.x;
    const int u0 = b * 16 + 2 * w;
    cg::grid_group grid = cg::this_grid();

    // Register-resident rows: f,i gates for both units (static-indexed arrays)
    int rfA[16], riA[16], rfB[16], riB[16];

    // ---------------- Phase A1: residency staging (fp8 regs + fp8 LDS) -------
    STAGE_REG_ROW(rfA, 0 * HS + u0);
    STAGE_REG_ROW(riA, 1 * HS + u0);
    STAGE_REG_ROW(rfB, 0 * HS + u0 + 1);
    STAGE_REG_ROW(riB, 1 * HS + u0 + 1);
    STAGE_LDS_ROW(4 * w + 0, 2 * HS + u0);        // cA
    STAGE_LDS_ROW(4 * w + 1, 3 * HS + u0);        // oA
    STAGE_LDS_ROW(4 * w + 2, 2 * HS + u0 + 1);    // cB
    STAGE_LDS_ROW(4 * w + 3, 3 * HS + u0 + 1);    // oB

    // ---------------- Phase A2: x-dots for the 8 rows, all 4 timesteps --------
    {
        int rid[8];
        rid[0] = 0 * HS + u0;     rid[1] = 1 * HS + u0;     rid[2] = 2 * HS + u0;
        rid[3] = 0 * HS + u0 + 1; rid[4] = 1 * HS + u0 + 1; rid[5] = 2 * HS + u0 + 1;
        rid[6] = 3 * HS + u0;     rid[7] = 3 * HS + u0 + 1;
        const int gate_of[8] = {0, 1, 2, 0, 1, 2, 3, 3};
        const int unit_of[8] = {0, 0, 0, 1, 1, 1, 0, 1};
        const float4* xv4 = reinterpret_cast<const float4*>(x);
#pragma unroll
        for (int r = 0; r < 8; ++r) {
            const float4* xr4 = reinterpret_cast<const float4*>(weight + (size_t)rid[r] * ZD + HS);
            float a0 = 0.f, a1 = 0.f, a2 = 0.f, a3 = 0.f;
#pragma unroll
            for (int i = 0; i < 8; ++i) {
                float4 wv = ldnt(&xr4[64 * i + l]);
                float4 x0 = xv4[0 * 512 + 64 * i + l];
                float4 x1 = xv4[1 * 512 + 64 * i + l];
                float4 x2 = xv4[2 * 512 + 64 * i + l];
                float4 x3 = xv4[3 * 512 + 64 * i + l];
                a0 += wv.x * x0.x + wv.y * x0.y + wv.z * x0.z + wv.w * x0.w;
                a1 += wv.x * x1.x + wv.y * x1.y + wv.z * x1.z + wv.w * x1.w;
                a2 += wv.x * x2.x + wv.y * x2.y + wv.z * x2.z + wv.w * x2.w;
                a3 += wv.x * x3.x + wv.y * x3.y + wv.z * x3.z + wv.w * x3.w;
            }
            a0 = wave_reduce(a0); a1 = wave_reduce(a1);
            a2 = wave_reduce(a2); a3 = wave_reduce(a3);
            if (l == 0) {
                const float bb = bias[rid[r]];
                gxbuf[w][unit_of[r]][gate_of[r]][0] = a0 + bb;
                gxbuf[w][unit_of[r]][gate_of[r]][1] = a1 + bb;
                gxbuf[w][unit_of[r]][gate_of[r]][2] = a2 + bb;
                gxbuf[w][unit_of[r]][gate_of[r]][3] = a3 + bb;
            }
        }
    }
    __syncthreads();

    // ---------------- Phase B: t=0 (h0=0, c0=0) ----------------
    if (l == 0) {
#pragma unroll
        for (int ui = 0; ui < 2; ++ui) {
            const int u = u0 + ui;
            const float gi = gxbuf[w][ui][1][0];
            const float gc = gxbuf[w][ui][2][0];
            const float go = gxbuf[w][ui][3][0];
            const float cn = tanhf(gc) * sigf(gi);
            cvs[2 * w + ui] = cn;
            H[u] = tanhf(cn) * sigf(go);
        }
    }
    grid.sync();

    // ---------------- Phase C: t = 1..3, W_h resident on-chip ----------------
    for (int t = 1; t < NT; ++t) {
        const float4* hp4 = reinterpret_cast<const float4*>(H + (size_t)(t - 1) * HS);
        float4* hb4 = reinterpret_cast<float4*>(hbuf);
        for (int i = tid; i < HS / 4; i += 512) hb4[i] = hp4[i];
        __syncthreads();

        float aFA = 0.f, aIA = 0.f, aCA = 0.f, aOA = 0.f;
        float aFB = 0.f, aIB = 0.f, aCB = 0.f, aOB = 0.f;
#pragma unroll
        for (int j = 0; j < 16; ++j) {
            const float4 h4 = hb4[64 * j + l];
            ACC_REG(rfA, aFA);
            ACC_REG(riA, aIA);
            ACC_REG(rfB, aFB);
            ACC_REG(riB, aIB);
            ACC_LDS(4 * w + 0, aCA);
            ACC_LDS(4 * w + 1, aOA);
            ACC_LDS(4 * w + 2, aCB);
            ACC_LDS(4 * w + 3, aOB);
        }
        aFA = wave_reduce(aFA); aIA = wave_reduce(aIA);
        aCA = wave_reduce(aCA); aOA = wave_reduce(aOA);
        aFB = wave_reduce(aFB); aIB = wave_reduce(aIB);
        aCB = wave_reduce(aCB); aOB = wave_reduce(aOB);

        if (l == 0) {
            {
                const float gf = aFA + gxbuf[w][0][0][t];
                const float gi = aIA + gxbuf[w][0][1][t];
                const float gc = aCA + gxbuf[w][0][2][t];
                const float go = aOA + gxbuf[w][0][3][t];
                const float cn = cvs[2 * w] * sigf(gf) + tanhf(gc) * sigf(gi);
                cvs[2 * w] = cn;
                H[(size_t)t * HS + u0] = tanhf(cn) * sigf(go);
            }
            {
                const float gf = aFB + gxbuf[w][1][0][t];
                const float gi = aIB + gxbuf[w][1][1][t];
                const float gc = aCB + gxbuf[w][1][2][t];
                const float go = aOB + gxbuf[w][1][3][t];
                const float cn = cvs[2 * w + 1] * sigf(gf) + tanhf(gc) * sigf(gi);
                cvs[2 * w + 1] = cn;
                H[(size_t)t * HS + u0 + 1] = tanhf(cn) * sigf(go);
            }
        }
        grid.sync();
    }

    // ---------------- Phase D: logits (1 row per wave, 256*8 = 2048) ----------
    {
        const int row = b * 8 + w;
        const float4* wrow4 = reinterpret_cast<const float4*>(W + (size_t)row * HS);
        const float4* H4 = reinterpret_cast<const float4*>(H);
        float a0 = 0.f, a1 = 0.f, a2 = 0.f, a3 = 0.f;
#pragma unroll
        for (int i = 0; i < 16; ++i) {
            const float4 wv = ldnt(&wrow4[64 * i + l]);
            const float4 h0 = H4[0 * 1024 + 64 * i + l];
            const float4 h1 = H4[1 * 1024 + 64 * i + l];
            const float4 h2 = H4[2 * 1024 + 64 * i + l];
            const float4 h3 = H4[3 * 1024 + 64 * i + l];
            a0 += wv.x * h0.x + wv.y * h0.y + wv.z * h0.z + wv.w * h0.w;
            a1 += wv.x * h1.x + wv.y * h1.y + wv.z * h1.z + wv.w * h1.w;
            a2 += wv.x * h2.x + wv.y * h2.y + wv.z * h2.z + wv.w * h2.w;
            a3 += wv.x * h3.x + wv.y * h3.y + wv.z * h3.z + wv.w * h3.w;
        }
        a0 = wave_reduce(a0); a1 = wave_reduce(a1);
        a2 = wave_reduce(a2); a3 = wave_reduce(a3);
        if (l == 0) {
            const float bv = bvec[row];
            logits[0 * IS + row] = a0 + bv;
            logits[1 * IS + row] = a1 + bv;
            logits[2 * IS + row] = a2 + bv;
            logits[3 * IS + row] = a3 + bv;
        }
    }
    grid.sync();

    // ---------------- Phase E: loss (block 0) ----------------
    if (b == 0) {
        float total = 0.f;
        for (int t = 0; t < NT; ++t) {
            const float* row = logits + (size_t)t * IS;
            float m = -1e30f;
            for (int r = tid; r < IS; r += 512) m = fmaxf(m, row[r]);
            red[tid] = m;
            __syncthreads();
            for (int s = 256; s > 0; s >>= 1) {
                if (tid < s) red[tid] = fmaxf(red[tid], red[tid + s]);
                __syncthreads();
            }
            m = red[0];
            __syncthreads();
            float sum = 0.f;
            for (int r = tid; r < IS; r += 512) sum += expf(row[r] - m);
            red[tid] = sum;
            __syncthreads();
            for (int s = 256; s > 0; s >>= 1) {
                if (tid < s) red[tid] += red[tid + s];
                __syncthreads();
            }
            if (tid == 0) total += (m + logf(red[0])) - row[target[t]];
            __syncthreads();
        }
        if (tid == 0) out[0] = total;
    }
}

extern "C" void kernel_launch(void* const* d_in, const int* in_sizes, int n_in,
                              void* d_out, int out_size, void* d_ws, size_t ws_size,
                              hipStream_t stream) {
    const float* x      = (const float*)d_in[0];   // [4][1][2048]
    const int*   target = (const int*)  d_in[1];   // [4][1]
    const float* weight = (const float*)d_in[2];   // [16384][6144]
    const float* bias   = (const float*)d_in[3];   // [16384]
    const float* W      = (const float*)d_in[4];   // [2048][4096]
    const float* bvec   = (const float*)d_in[5];   // [2048]
    float* out = (float*)d_out;

    float* H      = (float*)d_ws;                  // 4*4096 floats
    float* logits = (float*)d_ws + 4 * HS;         // 4*2048 floats

    void* args[] = {(void*)&x, (void*)&target, (void*)&weight, (void*)&bias,
                    (void*)&W, (void*)&bvec, (void*)&out, (void*)&H, (void*)&logits};
    (void)hipLaunchCooperativeKernel((void*)lstm_all, dim3(256), dim3(512), args, 0, stream);
}

// Round 7
// 197.163 us; speedup vs baseline: 2.6582x; 1.7760x over previous
//
#include <hip/hip_runtime.h>
#include <math.h>

#define HS 4096
#define IS 2048
#define NT 4
#define NR 16384   // 4*HS
#define ZD 6144    // HS+IS

typedef float fvec4 __attribute__((ext_vector_type(4)));
typedef float ef2 __attribute__((ext_vector_type(2)));

__device__ __forceinline__ float wave_reduce(float v) {
#pragma unroll
    for (int off = 32; off > 0; off >>= 1) v += __shfl_xor(v, off, 64);
    return v;
}
__device__ __forceinline__ float sigf(float x) { return 1.0f / (1.0f + expf(-x)); }

static __device__ __forceinline__ float4 ldnt(const float4* p) {
    fvec4 v = __builtin_nontemporal_load(reinterpret_cast<const fvec4*>(p));
    return make_float4(v.x, v.y, v.z, v.w);
}

// A: Gx[t][r] = bias[r] + sum_i Wx[r][i] * x[t][i]   for all t at once
__global__ __launch_bounds__(256) void gx_kernel(
    const float* __restrict__ x,       // [4][2048]
    const float* __restrict__ weight,  // [16384][6144]; x-part cols [4096,6144)
    const float* __restrict__ bias,    // [16384]
    float* __restrict__ Gx)            // [4][16384]
{
    __shared__ float xs[NT * IS];      // 32 KB
    const int tid = threadIdx.x;
    for (int i = tid; i < NT * IS; i += 256) xs[i] = x[i];
    __syncthreads();

    const int wave = tid >> 6, lane = tid & 63;
    const int r = blockIdx.x * 4 + wave;
    const float4* wrow = reinterpret_cast<const float4*>(weight + (size_t)r * ZD + HS);
    const float4* xs4 = reinterpret_cast<const float4*>(xs);

    float a0 = 0.f, a1 = 0.f, a2 = 0.f, a3 = 0.f;
#pragma unroll
    for (int it = 0; it < (IS / 4) / 64; ++it) {   // 8 iters
        const int e = it * 64 + lane;
        const float4 w = ldnt(&wrow[e]);
        const float4 p = xs4[e];
        const float4 q = xs4[(IS / 4) + e];
        const float4 s = xs4[2 * (IS / 4) + e];
        const float4 u = xs4[3 * (IS / 4) + e];
        a0 += w.x * p.x + w.y * p.y + w.z * p.z + w.w * p.w;
        a1 += w.x * q.x + w.y * q.y + w.z * q.z + w.w * q.w;
        a2 += w.x * s.x + w.y * s.y + w.z * s.z + w.w * s.w;
        a3 += w.x * u.x + w.y * u.y + w.z * u.z + w.w * u.w;
    }
    a0 = wave_reduce(a0); a1 = wave_reduce(a1);
    a2 = wave_reduce(a2); a3 = wave_reduce(a3);
    if (lane == 0) {
        const float bb = bias[r];
        Gx[0 * NR + r] = a0 + bb;
        Gx[1 * NR + r] = a1 + bb;
        Gx[2 * NR + r] = a2 + bb;
        Gx[3 * NR + r] = a3 + bb;
    }
}

// B: t=0 gates (h0=0, c0=0 => c = tanh(gc)*sig(gi))
__global__ __launch_bounds__(256) void step0_kernel(
    const float* __restrict__ Gx,      // [4][16384], t=0 slice
    float* __restrict__ H0,            // [4096]
    float* __restrict__ cvec)          // [4096]
{
    const int j = blockIdx.x * 256 + threadIdx.x;
    const float gi = Gx[HS + j];
    const float gc = Gx[2 * HS + j];
    const float go = Gx[3 * HS + j];
    const float cn = tanhf(gc) * sigf(gi);
    cvec[j] = cn;
    H0[j] = tanhf(cn) * sigf(go);
}

// C1 (t=1): fp32 W_h matvec + write packed-fp8 copy of W_h for steps 2,3
__global__ __launch_bounds__(256) void steph_conv_kernel(
    const float* __restrict__ weight,  // [16384][6144]; h-part cols [0,4096)
    const float* __restrict__ Gx,      // [4][16384]
    const float* __restrict__ Hprev,   // [4096]
    float* __restrict__ Hout,          // [4096]
    float* __restrict__ cvec,          // [4096]
    unsigned int* __restrict__ Whb8)   // [16384][1024] packed fp8
{
    __shared__ __align__(16) float hs_[HS];  // 16 KB
    const int tid = threadIdx.x;
    {
        const float4* hp4 = reinterpret_cast<const float4*>(Hprev);
        float4* hb4 = reinterpret_cast<float4*>(hs_);
        for (int i = tid; i < HS / 4; i += 256) hb4[i] = hp4[i];
    }
    __syncthreads();

    const int wave = tid >> 6, lane = tid & 63;
    const int j = blockIdx.x * 4 + wave;
    const float4* h4 = reinterpret_cast<const float4*>(hs_);

    float acc[4];
#pragma unroll
    for (int k = 0; k < 4; ++k) {
        const int row = k * HS + j;
        const float4* wrow = reinterpret_cast<const float4*>(weight + (size_t)row * ZD);
        unsigned int* wout = Whb8 + (size_t)row * 1024;
        float a = 0.f;
#pragma unroll
        for (int it = 0; it < 16; ++it) {
            const int e = it * 64 + lane;
            const float4 w = ldnt(&wrow[e]);
            const float4 h = h4[e];
            a += w.x * h.x + w.y * h.y + w.z * h.z + w.w * h.w;
            int u = __builtin_amdgcn_cvt_pk_fp8_f32(w.x, w.y, 0, false);
            u = __builtin_amdgcn_cvt_pk_fp8_f32(w.z, w.w, u, true);
            wout[e] = (unsigned int)u;
        }
        acc[k] = a;
    }
#pragma unroll
    for (int k = 0; k < 4; ++k) acc[k] = wave_reduce(acc[k]);

    if (lane == 0) {
        const size_t gb = (size_t)1 * NR;
        const float gf = acc[0] + Gx[gb + j];
        const float gi = acc[1] + Gx[gb + HS + j];
        const float gc = acc[2] + Gx[gb + 2 * HS + j];
        const float go = acc[3] + Gx[gb + 3 * HS + j];
        const float cn = cvec[j] * sigf(gf) + tanhf(gc) * sigf(gi);
        cvec[j] = cn;
        Hout[j] = tanhf(cn) * sigf(go);
    }
}

// C2 (t=2,3): packed-fp8 W_h matvec (reads Whb8, expected L3-resident)
__global__ __launch_bounds__(256) void steph_fp8_kernel(
    const unsigned int* __restrict__ Whb8,  // [16384][1024] packed fp8
    const float* __restrict__ Gx,           // [4][16384]
    const float* __restrict__ Hprev,        // [4096]
    float* __restrict__ Hout,               // [4096]
    float* __restrict__ cvec,               // [4096]
    const int t)
{
    __shared__ __align__(16) float hs_[HS];  // 16 KB
    const int tid = threadIdx.x;
    {
        const float4* hp4 = reinterpret_cast<const float4*>(Hprev);
        float4* hb4 = reinterpret_cast<float4*>(hs_);
        for (int i = tid; i < HS / 4; i += 256) hb4[i] = hp4[i];
    }
    __syncthreads();

    const int wave = tid >> 6, lane = tid & 63;
    const int j = blockIdx.x * 4 + wave;
    const float4* h4 = reinterpret_cast<const float4*>(hs_);

    const unsigned int* w0 = Whb8 + (size_t)(0 * HS + j) * 1024;
    const unsigned int* w1 = Whb8 + (size_t)(1 * HS + j) * 1024;
    const unsigned int* w2 = Whb8 + (size_t)(2 * HS + j) * 1024;
    const unsigned int* w3 = Whb8 + (size_t)(3 * HS + j) * 1024;

    float a0 = 0.f, a1 = 0.f, a2 = 0.f, a3 = 0.f;
#pragma unroll
    for (int it = 0; it < 16; ++it) {
        const int e = it * 64 + lane;
        const float4 h = h4[e];
        {
            const int u = (int)w0[e];
            const ef2 lo = __builtin_amdgcn_cvt_pk_f32_fp8(u, false);
            const ef2 hi = __builtin_amdgcn_cvt_pk_f32_fp8(u, true);
            a0 += lo.x * h.x + lo.y * h.y + hi.x * h.z + hi.y * h.w;
        }
        {
            const int u = (int)w1[e];
            const ef2 lo = __builtin_amdgcn_cvt_pk_f32_fp8(u, false);
            const ef2 hi = __builtin_amdgcn_cvt_pk_f32_fp8(u, true);
            a1 += lo.x * h.x + lo.y * h.y + hi.x * h.z + hi.y * h.w;
        }
        {
            const int u = (int)w2[e];
            const ef2 lo = __builtin_amdgcn_cvt_pk_f32_fp8(u, false);
            const ef2 hi = __builtin_amdgcn_cvt_pk_f32_fp8(u, true);
            a2 += lo.x * h.x + lo.y * h.y + hi.x * h.z + hi.y * h.w;
        }
        {
            const int u = (int)w3[e];
            const ef2 lo = __builtin_amdgcn_cvt_pk_f32_fp8(u, false);
            const ef2 hi = __builtin_amdgcn_cvt_pk_f32_fp8(u, true);
            a3 += lo.x * h.x + lo.y * h.y + hi.x * h.z + hi.y * h.w;
        }
    }
    a0 = wave_reduce(a0); a1 = wave_reduce(a1);
    a2 = wave_reduce(a2); a3 = wave_reduce(a3);

    if (lane == 0) {
        const size_t gb = (size_t)t * NR;
        const float gf = a0 + Gx[gb + j];
        const float gi = a1 + Gx[gb + HS + j];
        const float gc = a2 + Gx[gb + 2 * HS + j];
        const float go = a3 + Gx[gb + 3 * HS + j];
        const float cn = cvec[j] * sigf(gf) + tanhf(gc) * sigf(gi);
        cvec[j] = cn;
        Hout[j] = tanhf(cn) * sigf(go);
    }
}

// D: logits[t][r] = b[r] + sum_i W[r][i] * H[t][i]
__global__ __launch_bounds__(256) void logits_kernel(
    const float* __restrict__ W,       // [2048][4096]
    const float* __restrict__ bvec,    // [2048]
    const float* __restrict__ H,       // [4][4096]
    float* __restrict__ logits)        // [4][2048]
{
    const int wave = threadIdx.x >> 6, lane = threadIdx.x & 63;
    const int r = blockIdx.x * 4 + wave;
    const float4* wrow = reinterpret_cast<const float4*>(W + (size_t)r * HS);
    const float4* H4 = reinterpret_cast<const float4*>(H);

    float acc[4] = {0.f, 0.f, 0.f, 0.f};
#pragma unroll
    for (int it = 0; it < 16; ++it) {
        const int e = it * 64 + lane;
        const float4 w = ldnt(&wrow[e]);
#pragma unroll
        for (int t = 0; t < 4; ++t) {
            const float4 h = H4[t * (HS / 4) + e];
            acc[t] += w.x * h.x + w.y * h.y + w.z * h.z + w.w * h.w;
        }
    }
#pragma unroll
    for (int t = 0; t < 4; ++t) acc[t] = wave_reduce(acc[t]);
    if (lane == 0) {
        const float bv = bvec[r];
#pragma unroll
        for (int t = 0; t < 4; ++t) logits[t * IS + r] = acc[t] + bv;
    }
}

// E: loss = sum_t ( logsumexp(logits[t]) - logits[t][target[t]] )
__global__ __launch_bounds__(256) void loss_kernel(
    const float* __restrict__ logits,  // [4][2048]
    const int* __restrict__ target,    // [4]
    float* __restrict__ out)
{
    __shared__ float red[256];
    const int tid = threadIdx.x;
    float total = 0.f;
    for (int t = 0; t < NT; ++t) {
        const float* row = logits + (size_t)t * IS;
        float m = -1e30f;
        for (int r = tid; r < IS; r += 256) m = fmaxf(m, row[r]);
        red[tid] = m;
        __syncthreads();
        for (int s = 128; s > 0; s >>= 1) {
            if (tid < s) red[tid] = fmaxf(red[tid], red[tid + s]);
            __syncthreads();
        }
        m = red[0];
        __syncthreads();
        float sum = 0.f;
        for (int r = tid; r < IS; r += 256) sum += expf(row[r] - m);
        red[tid] = sum;
        __syncthreads();
        for (int s = 128; s > 0; s >>= 1) {
            if (tid < s) red[tid] += red[tid + s];
            __syncthreads();
        }
        if (tid == 0) total += (m + logf(red[0])) - row[target[t]];
        __syncthreads();
    }
    if (tid == 0) out[0] = total;
}

extern "C" void kernel_launch(void* const* d_in, const int* in_sizes, int n_in,
                              void* d_out, int out_size, void* d_ws, size_t ws_size,
                              hipStream_t stream) {
    const float* x      = (const float*)d_in[0];   // [4][1][2048]
    const int*   target = (const int*)  d_in[1];   // [4][1]
    const float* weight = (const float*)d_in[2];   // [16384][6144]
    const float* bias   = (const float*)d_in[3];   // [16384]
    const float* W      = (const float*)d_in[4];   // [2048][4096]
    const float* bvec   = (const float*)d_in[5];   // [2048]
    float* out = (float*)d_out;

    // workspace: fp8 W_h copy first (64 MB), then fp32 scratch
    unsigned int* Whb8 = (unsigned int*)d_ws;                    // 16384*1024 dwords
    float* fws = (float*)((char*)d_ws + (size_t)NR * 1024 * 4);
    float* Gx     = fws;                                         // 4*16384
    float* H      = fws + 65536;                                 // 4*4096
    float* cvec   = fws + 65536 + 16384;                         // 4096
    float* logits = fws + 65536 + 16384 + 4096;                  // 4*2048

    hipLaunchKernelGGL(gx_kernel, dim3(NR / 4), dim3(256), 0, stream, x, weight, bias, Gx);
    hipLaunchKernelGGL(step0_kernel, dim3(HS / 256), dim3(256), 0, stream, Gx, H, cvec);
    hipLaunchKernelGGL(steph_conv_kernel, dim3(HS / 4), dim3(256), 0, stream,
                       weight, Gx, H, H + HS, cvec, Whb8);
    hipLaunchKernelGGL(steph_fp8_kernel, dim3(HS / 4), dim3(256), 0, stream,
                       Whb8, Gx, H + HS, H + 2 * HS, cvec, 2);
    hipLaunchKernelGGL(steph_fp8_kernel, dim3(HS / 4), dim3(256), 0, stream,
                       Whb8, Gx, H + 2 * HS, H + 3 * HS, cvec, 3);
    hipLaunchKernelGGL(logits_kernel, dim3(IS / 4), dim3(256), 0, stream, W, bvec, H, logits);
    hipLaunchKernelGGL(loss_kernel, dim3(1), dim3(256), 0, stream, logits, target, out);
}